// Round 7
// baseline (579.613 us; speedup 1.0000x reference)
//
#include <hip/hip_runtime.h>

typedef _Float16 f16;
typedef _Float16 f16x8 __attribute__((ext_vector_type(8)));
typedef _Float16 f16x4 __attribute__((ext_vector_type(4)));
typedef _Float16 f16x2 __attribute__((ext_vector_type(2)));
typedef float f32x4 __attribute__((ext_vector_type(4)));

#define MFMA16(A,B,C) __builtin_amdgcn_mfma_f32_16x16x32_f16(A,B,C,0,0,0)
#define INV2048 4.8828125e-4f
#define HN (16ll*2048*96)

__device__ __forceinline__ void split_f16(float x, f16& h, f16& l) {
    h = (f16)x;
    l = (f16)((x - (float)h) * 2048.0f);   // lo pre-scaled by 2^11
}
__device__ __forceinline__ float rmax16(float v) {
    v = fmaxf(v, __shfl_xor(v, 1)); v = fmaxf(v, __shfl_xor(v, 2));
    v = fmaxf(v, __shfl_xor(v, 4)); v = fmaxf(v, __shfl_xor(v, 8));
    return v;
}
__device__ __forceinline__ float rsum16(float v) {
    v += __shfl_xor(v, 1); v += __shfl_xor(v, 2);
    v += __shfl_xor(v, 4); v += __shfl_xor(v, 8);
    return v;
}

// ============================================================
// K1: fp32-VALU dual GEMM qz@U^T, qz@V^T + RoPE; bitwise round-3
// per-output FMA chain (e-order preserved). m-tile 32, grid 1024
// (4 blocks/CU vs round-3's grid-capped 2).
// ============================================================
__global__ __launch_bounds__(256, 4) void k1_proj(const float* __restrict__ qz,
                                                  const float* __restrict__ U,
                                                  const float* __restrict__ V,
                                                  const float* __restrict__ cosb,
                                                  const float* __restrict__ sinb,
                                                  f16* __restrict__ uhp, f16* __restrict__ ulp,
                                                  f16* __restrict__ vhp, f16* __restrict__ vlp,
                                                  f16* __restrict__ vT, f16* __restrict__ oT) {
    __shared__ float At[32 * 32];   // qz tile natural [i][e], chunk-swizzled
    __shared__ float Bu[96 * 36];   // U rows natural [j][e]
    __shared__ float Bv[96 * 36];
    const int tid = threadIdx.x;
    const int ty = tid >> 4, tx = tid & 15;
    const int bs0 = blockIdx.x * 32;
    const int c = blockIdx.y;
    const int b = bs0 >> 11, s0 = bs0 & 2047;
    const int head = b * 8 + c;

    float accU[2][6] = {};
    float accV[2][6] = {};

    for (int e0 = 0; e0 < 768; e0 += 32) {
        __syncthreads();
        {
            int i = tid >> 3, ec = tid & 7;
            float4 v = *(const float4*)(qz + (size_t)(bs0 + i) * 768 + e0 + 4 * ec);
            *(float4*)&At[i * 32 + ((ec ^ ((i >> 2) & 7)) << 2)] = v;
        }
#pragma unroll
        for (int m = 0; m < 3; ++m) {
            int f = tid + 256 * m;
            int j = f >> 3, ec = f & 7;
            *(float4*)&Bu[j * 36 + 4 * ec] =
                *(const float4*)(U + (size_t)(c * 96 + j) * 768 + e0 + 4 * ec);
            *(float4*)&Bv[j * 36 + 4 * ec] =
                *(const float4*)(V + (size_t)(c * 96 + j) * 768 + e0 + 4 * ec);
        }
        __syncthreads();
#pragma unroll
        for (int ec = 0; ec < 8; ++ec) {
            float av[2][4];
#pragma unroll
            for (int ii = 0; ii < 2; ++ii) {
                int row = 2 * ty + ii;
                float4 a = *(const float4*)&At[row * 32 + ((ec ^ ((row >> 2) & 7)) << 2)];
                av[ii][0] = a.x; av[ii][1] = a.y; av[ii][2] = a.z; av[ii][3] = a.w;
            }
#pragma unroll
            for (int jj = 0; jj < 6; ++jj) {
                int j = tx + 16 * jj;
                float4 bu = *(const float4*)&Bu[j * 36 + 4 * ec];
                float4 bv = *(const float4*)&Bv[j * 36 + 4 * ec];
                float buv[4] = {bu.x, bu.y, bu.z, bu.w};
                float bvv[4] = {bv.x, bv.y, bv.z, bv.w};
#pragma unroll
                for (int ee = 0; ee < 4; ++ee)
#pragma unroll
                    for (int ii = 0; ii < 2; ++ii) {
                        accU[ii][jj] = fmaf(av[ii][ee], buv[ee], accU[ii][jj]);
                        accV[ii][jj] = fmaf(av[ii][ee], bvv[ee], accV[ii][jj]);
                    }
            }
        }
    }
    // epilogue: RoPE in fp32 (bitwise round-3), hi/lo split, stores
    const size_t nb = (size_t)head * 2048 * 96;
    const size_t tb = (size_t)head * 96 * 2048;
#pragma unroll
    for (int jj = 0; jj < 3; ++jj) {
        int r = tx + 16 * jj;
        f16 vt1[2], vt2[2], ot1[2], ot2[2];
#pragma unroll
        for (int ii = 0; ii < 2; ++ii) {
            int s = s0 + 2 * ty + ii;
            int cbi = (b * 2048 + s) * 96 + r;
            float cc = cosb[cbi], ss = sinb[cbi];
            size_t rowb = nb + (size_t)s * 96;
            float u1 = accU[ii][jj], u2 = accU[ii][jj + 3];
            float v1 = accV[ii][jj], v2 = accV[ii][jj + 3];
            float ur1 = u1 * cc - u2 * ss, ur2 = u2 * cc + u1 * ss;
            float uo1 = u1 * cc + u2 * ss, uo2 = u2 * cc - u1 * ss;
            float vr1 = v1 * cc - v2 * ss, vr2 = v2 * cc + v1 * ss;
            f16 h, l;
            split_f16(ur1, h, l); uhp[rowb + r] = h;      ulp[rowb + r] = l;
            split_f16(ur2, h, l); uhp[rowb + r + 48] = h; ulp[rowb + r + 48] = l;
            split_f16(vr1, h, l); vhp[rowb + r] = h;      vlp[rowb + r] = l;      vt1[ii] = h;
            split_f16(vr2, h, l); vhp[rowb + r + 48] = h; vlp[rowb + r + 48] = l; vt2[ii] = h;
            ot1[ii] = (f16)uo1; ot2[ii] = (f16)uo2;
        }
        f16x2 pv1 = {vt1[0], vt1[1]};
        f16x2 pv2 = {vt2[0], vt2[1]};
        f16x2 po1 = {ot1[0], ot1[1]};
        f16x2 po2 = {ot2[0], ot2[1]};
        *(f16x2*)&vT[tb + (size_t)r * 2048 + s0 + 2 * ty] = pv1;
        *(f16x2*)&vT[tb + (size_t)(r + 48) * 2048 + s0 + 2 * ty] = pv2;
        *(f16x2*)&oT[tb + (size_t)r * 2048 + s0 + 2 * ty] = po1;
        *(f16x2*)&oT[tb + (size_t)(r + 48) * 2048 + s0 + 2 * ty] = po2;
    }
}

// ============================================================
// K2: ROUND-3 VERBATIM. MFMA row stats, tile-level shuffle softmax.
// Do NOT touch: L summation order is part of the frozen numerics.
// ============================================================
__global__ __launch_bounds__(256, 2) void k2_stats(const f16* __restrict__ uhp,
                                                   const f16* __restrict__ ulp,
                                                   const f16* __restrict__ vhp,
                                                   const f16* __restrict__ vlp,
                                                   float* __restrict__ Mo,
                                                   float* __restrict__ Lo) {
    __shared__ f16 Bh[64 * 104];
    __shared__ f16 Bl[64 * 104];
    __shared__ float Mbuf[4][64], Lbuf[4][64];
    const int tid = threadIdx.x, w = tid >> 6, lane = tid & 63;
    const int quad = lane >> 4, l15 = lane & 15;
    const int q0 = blockIdx.x * 64, head = blockIdx.y;
    const f16* Ah_g = uhp + (size_t)head * 2048 * 96;
    const f16* Al_g = ulp + (size_t)head * 2048 * 96;
    const f16* Bh_g = vhp + (size_t)head * 2048 * 96;
    const f16* Bl_g = vlp + (size_t)head * 2048 * 96;

    f16x8 Afh[4][3], Afl[4][3];
#pragma unroll
    for (int mt = 0; mt < 4; ++mt)
#pragma unroll
        for (int cc = 0; cc < 3; ++cc) {
            size_t off = (size_t)(q0 + 16 * mt + l15) * 96 + cc * 32 + quad * 8;
            Afh[mt][cc] = *(const f16x8*)(Ah_g + off);
            Afl[mt][cc] = *(const f16x8*)(Al_g + off);
        }

    float m_run[4][4], l_run[4][4];
#pragma unroll
    for (int mt = 0; mt < 4; ++mt)
#pragma unroll
        for (int r = 0; r < 4; ++r) { m_run[mt][r] = -3.0e38f; l_run[mt][r] = 0.f; }

    for (int k0 = 0; k0 < 2048; k0 += 64) {
        __syncthreads();
#pragma unroll
        for (int m = 0; m < 3; ++m) {
            int f = tid + 256 * m;
            int row = f / 12, c12 = f % 12;
            *(float4*)&Bh[row * 104 + c12 * 8] =
                *(const float4*)(Bh_g + (size_t)(k0 + row) * 96 + c12 * 8);
            *(float4*)&Bl[row * 104 + c12 * 8] =
                *(const float4*)(Bl_g + (size_t)(k0 + row) * 96 + c12 * 8);
        }
        __syncthreads();
        f32x4 accS[4] = {}, accX[4] = {};
#pragma unroll
        for (int cc = 0; cc < 3; ++cc) {
            f16x8 bh = *(const f16x8*)&Bh[(w * 16 + l15) * 104 + cc * 32 + quad * 8];
            f16x8 bl = *(const f16x8*)&Bl[(w * 16 + l15) * 104 + cc * 32 + quad * 8];
#pragma unroll
            for (int mt = 0; mt < 4; ++mt) {
                accS[mt] = MFMA16(Afh[mt][cc], bh, accS[mt]);
                accX[mt] = MFMA16(Afh[mt][cc], bl, accX[mt]);
                accX[mt] = MFMA16(Afl[mt][cc], bh, accX[mt]);
            }
        }
#pragma unroll
        for (int mt = 0; mt < 4; ++mt)
#pragma unroll
            for (int r = 0; r < 4; ++r) {
                float z = 768.0f * (accS[mt][r] + accX[mt][r] * INV2048);
                float tm = rmax16(z);
                float e = rsum16(__expf(z - tm));
                float nm = fmaxf(m_run[mt][r], tm);
                l_run[mt][r] = l_run[mt][r] * __expf(m_run[mt][r] - nm) + e * __expf(tm - nm);
                m_run[mt][r] = nm;
            }
    }
    if (l15 == 0) {
#pragma unroll
        for (int mt = 0; mt < 4; ++mt)
#pragma unroll
            for (int r = 0; r < 4; ++r) {
                Mbuf[w][16 * mt + 4 * quad + r] = m_run[mt][r];
                Lbuf[w][16 * mt + 4 * quad + r] = l_run[mt][r];
            }
    }
    __syncthreads();
    if (tid < 64) {
        float M = -3.0e38f;
#pragma unroll
        for (int ww = 0; ww < 4; ++ww) M = fmaxf(M, Mbuf[ww][tid]);
        float L = 0.f;
#pragma unroll
        for (int ww = 0; ww < 4; ++ww) L += Lbuf[ww][tid] * __expf(Mbuf[ww][tid] - M);
        Mo[head * 2048 + q0 + tid] = M;
        Lo[head * 2048 + q0 + tid] = L;
    }
}

// ============================================================
// K3a: ROUND-3 VERBATIM.
// ============================================================
__global__ __launch_bounds__(256, 2) void k3a(const f16* __restrict__ uhp,
                                              const f16* __restrict__ ulp,
                                              const f16* __restrict__ vhp,
                                              const f16* __restrict__ vlp,
                                              const f16* __restrict__ vT,
                                              const float* __restrict__ Mo,
                                              const float* __restrict__ Lo,
                                              const float* __restrict__ cosb,
                                              const float* __restrict__ sinb,
                                              f16* __restrict__ w1) {
    __shared__ f16 Bh[64 * 104];
    __shared__ f16 Bl[64 * 104];
    __shared__ f16 Vt[96 * 72];
    __shared__ f16 P[64 * 72];
    const int tid = threadIdx.x, w = tid >> 6, lane = tid & 63;
    const int quad = lane >> 4, l15 = lane & 15;
    const int q0 = blockIdx.x * 64, head = blockIdx.y;
    const f16* Ah_g = uhp + (size_t)head * 2048 * 96;
    const f16* Al_g = ulp + (size_t)head * 2048 * 96;
    const f16* Bh_g = vhp + (size_t)head * 2048 * 96;
    const f16* Bl_g = vlp + (size_t)head * 2048 * 96;
    const f16* Vt_g = vT + (size_t)head * 96 * 2048;

    f16x8 Afh[4][3], Afl[4][3];
#pragma unroll
    for (int mt = 0; mt < 4; ++mt)
#pragma unroll
        for (int cc = 0; cc < 3; ++cc) {
            size_t off = (size_t)(q0 + 16 * mt + l15) * 96 + cc * 32 + quad * 8;
            Afh[mt][cc] = *(const f16x8*)(Ah_g + off);
            Afl[mt][cc] = *(const f16x8*)(Al_g + off);
        }
    float negM[4][4];
#pragma unroll
    for (int mt = 0; mt < 4; ++mt)
#pragma unroll
        for (int r = 0; r < 4; ++r)
            negM[mt][r] = -Mo[head * 2048 + q0 + 16 * mt + 4 * quad + r];
    float invL[4];
#pragma unroll
    for (int r = 0; r < 4; ++r)
        invL[r] = 1.0f / Lo[head * 2048 + q0 + w * 16 + quad * 4 + r];

    f32x4 accO[6] = {};

    for (int k0 = 0; k0 < 2048; k0 += 64) {
        __syncthreads();
#pragma unroll
        for (int m = 0; m < 3; ++m) {
            int f = tid + 256 * m;
            int row = f / 12, c12 = f % 12;
            *(float4*)&Bh[row * 104 + c12 * 8] =
                *(const float4*)(Bh_g + (size_t)(k0 + row) * 96 + c12 * 8);
            *(float4*)&Bl[row * 104 + c12 * 8] =
                *(const float4*)(Bl_g + (size_t)(k0 + row) * 96 + c12 * 8);
        }
#pragma unroll
        for (int m = 0; m < 3; ++m) {
            int f = tid + 256 * m;
            int row = f >> 3, c8 = f & 7;
            *(float4*)&Vt[row * 72 + c8 * 8] =
                *(const float4*)(Vt_g + (size_t)row * 2048 + k0 + c8 * 8);
        }
        __syncthreads();
        f32x4 accS[4] = {}, accX[4] = {};
#pragma unroll
        for (int cc = 0; cc < 3; ++cc) {
            f16x8 bh = *(const f16x8*)&Bh[(w * 16 + l15) * 104 + cc * 32 + quad * 8];
            f16x8 bl = *(const f16x8*)&Bl[(w * 16 + l15) * 104 + cc * 32 + quad * 8];
#pragma unroll
            for (int mt = 0; mt < 4; ++mt) {
                accS[mt] = MFMA16(Afh[mt][cc], bh, accS[mt]);
                accX[mt] = MFMA16(Afh[mt][cc], bl, accX[mt]);
                accX[mt] = MFMA16(Afl[mt][cc], bh, accX[mt]);
            }
        }
#pragma unroll
        for (int mt = 0; mt < 4; ++mt)
#pragma unroll
            for (int r = 0; r < 4; ++r) {
                float z = 768.0f * (accS[mt][r] + accX[mt][r] * INV2048);
                P[(16 * mt + 4 * quad + r) * 72 + w * 16 + l15] =
                    (f16)__expf(z + negM[mt][r]);
            }
        __syncthreads();
#pragma unroll
        for (int kc = 0; kc < 2; ++kc) {
            f16x8 ap = *(const f16x8*)&P[(w * 16 + l15) * 72 + kc * 32 + quad * 8];
#pragma unroll
            for (int nt = 0; nt < 6; ++nt) {
                f16x8 bv = *(const f16x8*)&Vt[(nt * 16 + l15) * 72 + kc * 32 + quad * 8];
                accO[nt] = MFMA16(ap, bv, accO[nt]);
            }
        }
        __syncthreads();
    }
    const int b = head >> 3, c = head & 7;
#pragma unroll
    for (int r = 0; r < 4; ++r) {
        int q = q0 + w * 16 + quad * 4 + r;
        int cbi = (b * 2048 + q) * 96;
        f16* wrow = w1 + (size_t)(b * 2048 + q) * 768 + c * 96;
#pragma unroll
        for (int nt = 0; nt < 3; ++nt) {
            int rr = nt * 16 + l15;
            float cc = cosb[cbi + rr], ss = sinb[cbi + rr];
            float a = accO[nt][r] * invL[r];
            float b2 = accO[nt + 3][r] * invL[r];
            wrow[rr] = (f16)(a * cc + b2 * ss);
            wrow[rr + 48] = (f16)(b2 * cc - a * ss);
        }
    }
}

// ============================================================
// K3b: ROUND-3 VERBATIM.
// ============================================================
__global__ __launch_bounds__(256, 2) void k3b(const f16* __restrict__ uhp,
                                              const f16* __restrict__ ulp,
                                              const f16* __restrict__ vhp,
                                              const f16* __restrict__ vlp,
                                              const f16* __restrict__ oT,
                                              const float* __restrict__ Mo,
                                              const float* __restrict__ Lo,
                                              const float* __restrict__ cosb,
                                              const float* __restrict__ sinb,
                                              f16* __restrict__ w2) {
    __shared__ f16 Bh[64 * 104];
    __shared__ f16 Bl[64 * 104];
    __shared__ f16 Ot[96 * 72];
    __shared__ f16 P[64 * 72];
    const int tid = threadIdx.x, w = tid >> 6, lane = tid & 63;
    const int quad = lane >> 4, l15 = lane & 15;
    const int q0 = blockIdx.x * 64, head = blockIdx.y;
    const f16* Ah_g = vhp + (size_t)head * 2048 * 96;   // A = vr
    const f16* Al_g = vlp + (size_t)head * 2048 * 96;
    const f16* Bh_g = uhp + (size_t)head * 2048 * 96;   // B = ur
    const f16* Bl_g = ulp + (size_t)head * 2048 * 96;
    const f16* Ot_g = oT + (size_t)head * 96 * 2048;

    f16x8 Afh[4][3], Afl[4][3];
#pragma unroll
    for (int mt = 0; mt < 4; ++mt)
#pragma unroll
        for (int cc = 0; cc < 3; ++cc) {
            size_t off = (size_t)(q0 + 16 * mt + l15) * 96 + cc * 32 + quad * 8;
            Afh[mt][cc] = *(const f16x8*)(Ah_g + off);
            Afl[mt][cc] = *(const f16x8*)(Al_g + off);
        }

    f32x4 accO[6] = {};

    for (int k0 = 0; k0 < 2048; k0 += 64) {
        float negMk = -Mo[head * 2048 + k0 + w * 16 + l15];
        float invLk = 1.0f / Lo[head * 2048 + k0 + w * 16 + l15];
        __syncthreads();
#pragma unroll
        for (int m = 0; m < 3; ++m) {
            int f = tid + 256 * m;
            int row = f / 12, c12 = f % 12;
            *(float4*)&Bh[row * 104 + c12 * 8] =
                *(const float4*)(Bh_g + (size_t)(k0 + row) * 96 + c12 * 8);
            *(float4*)&Bl[row * 104 + c12 * 8] =
                *(const float4*)(Bl_g + (size_t)(k0 + row) * 96 + c12 * 8);
        }
#pragma unroll
        for (int m = 0; m < 3; ++m) {
            int f = tid + 256 * m;
            int row = f >> 3, c8 = f & 7;
            *(float4*)&Ot[row * 72 + c8 * 8] =
                *(const float4*)(Ot_g + (size_t)row * 2048 + k0 + c8 * 8);
        }
        __syncthreads();
        f32x4 accS[4] = {}, accX[4] = {};
#pragma unroll
        for (int cc = 0; cc < 3; ++cc) {
            f16x8 bh = *(const f16x8*)&Bh[(w * 16 + l15) * 104 + cc * 32 + quad * 8];
            f16x8 bl = *(const f16x8*)&Bl[(w * 16 + l15) * 104 + cc * 32 + quad * 8];
#pragma unroll
            for (int mt = 0; mt < 4; ++mt) {
                accS[mt] = MFMA16(Afh[mt][cc], bh, accS[mt]);
                // preserve k2's cross-product order
                accX[mt] = MFMA16(Afl[mt][cc], bh, accX[mt]);   // v_lo * u_hi
                accX[mt] = MFMA16(Afh[mt][cc], bl, accX[mt]);   // v_hi * u_lo
            }
        }
#pragma unroll
        for (int mt = 0; mt < 4; ++mt)
#pragma unroll
            for (int r = 0; r < 4; ++r) {
                float z = 768.0f * (accS[mt][r] + accX[mt][r] * INV2048);
                P[(16 * mt + 4 * quad + r) * 72 + w * 16 + l15] =
                    (f16)(__expf(z + negMk) * invLk);
            }
        __syncthreads();
#pragma unroll
        for (int kc = 0; kc < 2; ++kc) {
            f16x8 ap = *(const f16x8*)&P[(w * 16 + l15) * 72 + kc * 32 + quad * 8];
#pragma unroll
            for (int nt = 0; nt < 6; ++nt) {
                f16x8 bo = *(const f16x8*)&Ot[(nt * 16 + l15) * 72 + kc * 32 + quad * 8];
                accO[nt] = MFMA16(ap, bo, accO[nt]);
            }
        }
        __syncthreads();
    }
    const int b = head >> 3, c = head & 7;
#pragma unroll
    for (int r = 0; r < 4; ++r) {
        int q = q0 + w * 16 + quad * 4 + r;
        int cbi = (b * 2048 + q) * 96;
        f16* wrow = w2 + (size_t)(b * 2048 + q) * 768 + c * 96;
#pragma unroll
        for (int nt = 0; nt < 3; ++nt) {
            int rr = nt * 16 + l15;
            float cc = cosb[cbi + rr], ss = sinb[cbi + rr];
            float a = accO[nt][r];
            float b2 = accO[nt + 3][r];
            wrow[rr] = (f16)(a * cc - b2 * ss);
            wrow[rr + 48] = (f16)(b2 * cc + a * ss);
        }
    }
}

// ============================================================
// K4: ROUND-3 VERBATIM. G = w1@U + w2@V (fp16 MFMA).
// ============================================================
__global__ __launch_bounds__(256, 2) void k4_final(const f16* __restrict__ w1,
                                                   const f16* __restrict__ w2,
                                                   const float* __restrict__ U,
                                                   const float* __restrict__ V,
                                                   float* __restrict__ outp) {
    __shared__ f16 A1[128 * 56];
    __shared__ f16 A2[128 * 56];
    __shared__ f16 B1[64 * 56];
    __shared__ f16 B2[64 * 56];
    const int tid = threadIdx.x, w = tid >> 6, lane = tid & 63;
    const int quad = lane >> 4, l15 = lane & 15;
    const int bs0 = blockIdx.x * 128;
    const int d0 = blockIdx.y * 64;
    f32x4 acc[2][4] = {};

    for (int ec = 0; ec < 24; ++ec) {
        int e0 = ec * 32;
        __syncthreads();
#pragma unroll
        for (int m = 0; m < 2; ++m) {
            int f = tid + 256 * m;
            int row = f >> 2, q = f & 3;
            *(float4*)&A1[row * 56 + q * 8] =
                *(const float4*)(w1 + (size_t)(bs0 + row) * 768 + e0 + q * 8);
            *(float4*)&A2[row * 56 + q * 8] =
                *(const float4*)(w2 + (size_t)(bs0 + row) * 768 + e0 + q * 8);
        }
#pragma unroll
        for (int m2 = 0; m2 < 2; ++m2) {
            int e_r = (tid >> 4) + 16 * m2;
            int dc = tid & 15;
            float4 fu = *(const float4*)(U + (size_t)(e0 + e_r) * 768 + d0 + dc * 4);
            float4 fv = *(const float4*)(V + (size_t)(e0 + e_r) * 768 + d0 + dc * 4);
            B1[(dc * 4 + 0) * 56 + e_r] = (f16)fu.x;
            B1[(dc * 4 + 1) * 56 + e_r] = (f16)fu.y;
            B1[(dc * 4 + 2) * 56 + e_r] = (f16)fu.z;
            B1[(dc * 4 + 3) * 56 + e_r] = (f16)fu.w;
            B2[(dc * 4 + 0) * 56 + e_r] = (f16)fv.x;
            B2[(dc * 4 + 1) * 56 + e_r] = (f16)fv.y;
            B2[(dc * 4 + 2) * 56 + e_r] = (f16)fv.z;
            B2[(dc * 4 + 3) * 56 + e_r] = (f16)fv.w;
        }
        __syncthreads();
        f16x8 a1f[2], a2f[2];
#pragma unroll
        for (int mt = 0; mt < 2; ++mt) {
            a1f[mt] = *(const f16x8*)&A1[(32 * w + 16 * mt + l15) * 56 + quad * 8];
            a2f[mt] = *(const f16x8*)&A2[(32 * w + 16 * mt + l15) * 56 + quad * 8];
        }
#pragma unroll
        for (int nt = 0; nt < 4; ++nt) {
            f16x8 b1f = *(const f16x8*)&B1[(nt * 16 + l15) * 56 + quad * 8];
            f16x8 b2f = *(const f16x8*)&B2[(nt * 16 + l15) * 56 + quad * 8];
#pragma unroll
            for (int mt = 0; mt < 2; ++mt) {
                acc[mt][nt] = MFMA16(a1f[mt], b1f, acc[mt][nt]);
                acc[mt][nt] = MFMA16(a2f[mt], b2f, acc[mt][nt]);
            }
        }
    }
#pragma unroll
    for (int mt = 0; mt < 2; ++mt)
#pragma unroll
        for (int nt = 0; nt < 4; ++nt)
#pragma unroll
            for (int r = 0; r < 4; ++r) {
                int s = bs0 + 32 * w + 16 * mt + 4 * quad + r;
                int d = d0 + 16 * nt + l15;
                outp[(size_t)s * 768 + d] = acc[mt][nt][r];
            }
}

extern "C" void kernel_launch(void* const* d_in, const int* in_sizes, int n_in,
                              void* d_out, int out_size, void* d_ws, size_t ws_size,
                              hipStream_t stream) {
    const float* qz   = (const float*)d_in[0];
    const float* cosb = (const float*)d_in[1];
    const float* sinb = (const float*)d_in[2];
    const float* U    = (const float*)d_in[3];
    const float* V    = (const float*)d_in[4];
    float* outp = (float*)d_out;

    f16* ws16 = (f16*)d_ws;
    f16* uhp = ws16;
    f16* ulp = ws16 + HN;
    f16* vhp = ws16 + 2 * HN;
    f16* vlp = ws16 + 3 * HN;
    f16* vT  = ws16 + 4 * HN;
    f16* oT  = ws16 + 5 * HN;
    f16* w1  = ws16 + 6 * HN;
    f16* w2  = ws16 + 7 * HN;
    float* Mo = (float*)(ws16 + 8 * HN);
    float* Lo = Mo + 16 * 2048;

    k1_proj<<<dim3(128, 8), 256, 0, stream>>>(qz, U, V, cosb, sinb,
                                              uhp, ulp, vhp, vlp, vT, oT);
    k2_stats<<<dim3(32, 16), 256, 0, stream>>>(uhp, ulp, vhp, vlp, Mo, Lo);
    k3a<<<dim3(32, 16), 256, 0, stream>>>(uhp, ulp, vhp, vlp, vT, Mo, Lo, cosb, sinb, w1);
    k3b<<<dim3(32, 16), 256, 0, stream>>>(uhp, ulp, vhp, vlp, oT, Mo, Lo, cosb, sinb, w2);
    k4_final<<<dim3(32, 12), 256, 0, stream>>>(w1, w2, U, V, outp);
}